// Round 5
// baseline (202.769 us; speedup 1.0000x reference)
//
#include <hip/hip_runtime.h>
#include <stdint.h>

typedef unsigned long long u64;

static constexpr int T = 1024;
static constexpr int B = 2;
static constexpr int N = 10000;
static constexpr int L = 30;
static constexpr int S = 2 * L + 1;   // 61

static constexpr int NBLK  = 2048;    // == B*T: one corr pair per block + one sweep chunk
static constexpr int CHUNK = 2500;    // float4 per block; 2048*2500 == T*B*N/4
static constexpr int TAIL  = CHUNK - 9 * 256;   // 196

static constexpr u64 ALL   = (1ULL << S) - 1;
static constexpr u64 EVENM = 0x5555555555555555ULL & ((1ULL << S) - 1);

__device__ __forceinline__ float block_reduce(float s) {
    for (int off = 32; off; off >>= 1) s += __shfl_down(s, off, 64);
    __shared__ float tmp[8];
    int lane = threadIdx.x & 63, w = threadIdx.x >> 6;
    int nw = blockDim.x >> 6;
    if (lane == 0) tmp[w] = s;
    __syncthreads();
    float t = 0.f;
    if (threadIdx.x == 0)
        for (int i = 0; i < nw; ++i) t += tmp[i];
    return t;
}

__device__ __forceinline__ float sq4(float4 v) {
    return v.x * v.x + v.y * v.y + v.z * v.z + v.w * v.w;
}

// Every block: (a) corr for its single (b,t) pair on wave-0 lanes 0..31
// (1 scattered load/lane; lattice bit-loop only for the 256 edge-t blocks),
// (b) sweep of one contiguous 2500-float4 chunk. Perfect balance.
// Final reduction folded in via last-block-done counter (one atomic per block
// on a counter — NOT the round-2 same-address-per-block-result bug).
__global__ void k_fused(const float4* __restrict__ x4, const float* __restrict__ x,
                        const int* __restrict__ label, float* __restrict__ partials,
                        unsigned* __restrict__ counter, float* __restrict__ out) {
    int tid = threadIdx.x;
    float s = 0.f;

    const int b = blockIdx.x >> 10;        // pair = blockIdx.x == b*T + t
    const int t = blockIdx.x & (T - 1);

    __shared__ int labs[L];
    if (tid < L) labs[tid] = label[b * L + tid];
    __syncthreads();

    if (tid < 32) {
        // lattice mask m for this (b,t) — wave-uniform, computed redundantly
        u64 m;
        if (t < 64) {
            // backward map saturated here (t <= T-61); forward needs t steps
            u64 Af = 0;
            #pragma unroll
            for (int k = 0; k < L; ++k)
                if (k == 0 || labs[k] != labs[k - 1]) Af |= 1ULL << (2 * k + 1);
            u64 c = 3ULL;
            for (int i = 0; i < t; ++i) c = (c | (c << 1) | ((c << 2) & Af)) & ALL;
            m = c;
        } else if (t >= T - 64) {
            // forward map saturated here (t >= 60); backward needs T-1-t steps
            u64 Ab = 0;
            #pragma unroll
            for (int k = 0; k < L; ++k)
                if (k == L - 1 || labs[k] != labs[k + 1]) Ab |= 1ULL << (2 * k + 1);
            u64 c = (1ULL << (S - 1)) | (1ULL << (S - 2));
            int n = T - 1 - t;
            for (int i = 0; i < n; ++i) c = c | (c >> 1) | ((c >> 2) & Ab);
            m = c;
        } else {
            m = ALL;
        }
        const float* row = x + (size_t)t * (B * N) + (size_t)b * N;
        if (tid < L) {
            u64 bit = 1ULL << (2 * tid + 1);
            if (m & bit) {
                int v = labs[tid];
                bool dup = false;
                for (int k2 = 0; k2 < tid; ++k2)
                    if (labs[k2] == v && (m & (1ULL << (2 * k2 + 1)))) { dup = true; break; }
                if (!dup) { float xv = row[v]; s -= xv * xv; }
            }
        } else if (tid == L) {
            if (m & EVENM) { float xv = row[0]; s -= xv * xv; }  // blank, once
        }
    }

    // Sweep: contiguous chunk, 9 full rounds + 196-thread tail; two 5-deep
    // independent load batches.
    const float4* p = x4 + (size_t)blockIdx.x * CHUNK + tid;
    float4 v[5];
    #pragma unroll
    for (int j = 0; j < 5; ++j) v[j] = p[j * 256];
    #pragma unroll
    for (int j = 0; j < 5; ++j) s += sq4(v[j]);
    #pragma unroll
    for (int j = 0; j < 4; ++j) v[j] = p[(5 + j) * 256];
    v[4] = (tid < TAIL) ? p[9 * 256] : make_float4(0.f, 0.f, 0.f, 0.f);
    #pragma unroll
    for (int j = 0; j < 5; ++j) s += sq4(v[j]);

    float tot = block_reduce(s);

    __shared__ bool isLast;
    if (tid == 0) {
        partials[blockIdx.x] = tot;
        __threadfence();                         // release partial (device scope)
        unsigned old = atomicAdd(counter, 1u);   // one atomic per block
        isLast = (old == NBLK - 1);
    }
    __syncthreads();
    if (isLast) {
        __threadfence();                         // acquire others' partials
        float s2 = 0.f;
        for (int i = tid; i < NBLK; i += 256) s2 += partials[i];
        float t2 = block_reduce(s2);
        if (tid == 0) out[0] = 0.5f * t2;
    }
}

extern "C" void kernel_launch(void* const* d_in, const int* in_sizes, int n_in,
                              void* d_out, int out_size, void* d_ws, size_t ws_size,
                              hipStream_t stream) {
    const float* logits = (const float*)d_in[0];
    const int*   label  = (const int*)d_in[2];
    float*    partials = (float*)d_ws;                       // NBLK floats
    unsigned* counter  = (unsigned*)((char*)d_ws + 8192);    // 4 bytes

    hipMemsetAsync(counter, 0, 4, stream);
    k_fused<<<NBLK, 256, 0, stream>>>((const float4*)logits, logits, label,
                                      partials, counter, (float*)d_out);
}

// Round 6
// 120.392 us; speedup vs baseline: 1.6842x; 1.6842x over previous
//
#include <hip/hip_runtime.h>
#include <stdint.h>

typedef unsigned long long u64;

static constexpr int T = 1024;
static constexpr int B = 2;
static constexpr int N = 10000;
static constexpr int L = 30;
static constexpr int S = 2 * L + 1;   // 61

static constexpr int NBLK  = 2048;    // == B*T: one corr pair per block + one sweep chunk
static constexpr int CHUNK = 2500;    // float4 per block; 2048*2500 == T*B*N/4
static constexpr int TAIL  = CHUNK - 9 * 256;   // 196

static constexpr u64 ALL   = (1ULL << S) - 1;
static constexpr u64 EVENM = 0x5555555555555555ULL & ((1ULL << S) - 1);

__device__ __forceinline__ float block_reduce(float s) {
    for (int off = 32; off; off >>= 1) s += __shfl_down(s, off, 64);
    __shared__ float tmp[8];
    int lane = threadIdx.x & 63, w = threadIdx.x >> 6;
    int nw = blockDim.x >> 6;
    if (lane == 0) tmp[w] = s;
    __syncthreads();
    float t = 0.f;
    if (threadIdx.x == 0)
        for (int i = 0; i < nw; ++i) t += tmp[i];
    return t;
}

__device__ __forceinline__ float sq4(float4 v) {
    return v.x * v.x + v.y * v.y + v.z * v.z + v.w * v.w;
}

// Every block: (a) corr for its single (b,t) pair on wave-0 lanes 0..31
// (1 scattered load/lane; lattice bit-loop only for the 256 edge-t blocks),
// (b) sweep of one contiguous 2500-float4 chunk (10-deep load batch).
// Per-block partial to distinct address. NO device-scope fences or
// same-address atomics per block (round-2: 2048 same-address atomicAdds
// ~= 50us; round-5: 2048 __threadfence L2-writebacks ~= 100us).
__global__ void __launch_bounds__(256, 8)
k_fused(const float4* __restrict__ x4, const float* __restrict__ x,
        const int* __restrict__ label, float* __restrict__ partials) {
    int tid = threadIdx.x;
    float s = 0.f;

    const int b = blockIdx.x >> 10;        // pair = blockIdx.x == b*T + t
    const int t = blockIdx.x & (T - 1);

    __shared__ int labs[L];
    if (tid < L) labs[tid] = label[b * L + tid];
    __syncthreads();

    if (tid < 32) {
        // lattice mask m for this (b,t) — wave-uniform, computed redundantly
        u64 m;
        if (t < 64) {
            // backward map saturated here (t <= T-61); forward needs t steps
            u64 Af = 0;
            #pragma unroll
            for (int k = 0; k < L; ++k)
                if (k == 0 || labs[k] != labs[k - 1]) Af |= 1ULL << (2 * k + 1);
            u64 c = 3ULL;
            for (int i = 0; i < t; ++i) c = (c | (c << 1) | ((c << 2) & Af)) & ALL;
            m = c;
        } else if (t >= T - 64) {
            // forward map saturated here (t >= 60); backward needs T-1-t steps
            u64 Ab = 0;
            #pragma unroll
            for (int k = 0; k < L; ++k)
                if (k == L - 1 || labs[k] != labs[k + 1]) Ab |= 1ULL << (2 * k + 1);
            u64 c = (1ULL << (S - 1)) | (1ULL << (S - 2));
            int n = T - 1 - t;
            for (int i = 0; i < n; ++i) c = c | (c >> 1) | ((c >> 2) & Ab);
            m = c;
        } else {
            m = ALL;
        }
        const float* row = x + (size_t)t * (B * N) + (size_t)b * N;
        if (tid < L) {
            u64 bit = 1ULL << (2 * tid + 1);
            if (m & bit) {
                int v = labs[tid];
                bool dup = false;
                for (int k2 = 0; k2 < tid; ++k2)
                    if (labs[k2] == v && (m & (1ULL << (2 * k2 + 1)))) { dup = true; break; }
                if (!dup) { float xv = row[v]; s -= xv * xv; }
            }
        } else if (tid == L) {
            if (m & EVENM) { float xv = row[0]; s -= xv * xv; }  // blank, once
        }
    }

    // Sweep: contiguous chunk, one 10-deep independent load batch (MLP 10),
    // 9 full rounds + 196-thread tail.
    const float4* p = x4 + (size_t)blockIdx.x * CHUNK + tid;
    float4 v[10];
    #pragma unroll
    for (int j = 0; j < 9; ++j) v[j] = p[j * 256];
    v[9] = (tid < TAIL) ? p[9 * 256] : make_float4(0.f, 0.f, 0.f, 0.f);
    #pragma unroll
    for (int j = 0; j < 10; ++j) s += sq4(v[j]);

    float tot = block_reduce(s);
    if (threadIdx.x == 0) partials[blockIdx.x] = tot;
}

// out = 0.5 * sum(partials)
__global__ void k_final(const float* __restrict__ partials, float* __restrict__ out) {
    float s = 0.f;
    for (int i = threadIdx.x; i < NBLK; i += 256) s += partials[i];
    float tot = block_reduce(s);
    if (threadIdx.x == 0) out[0] = 0.5f * tot;
}

extern "C" void kernel_launch(void* const* d_in, const int* in_sizes, int n_in,
                              void* d_out, int out_size, void* d_ws, size_t ws_size,
                              hipStream_t stream) {
    const float* logits = (const float*)d_in[0];
    const int*   label  = (const int*)d_in[2];
    float* partials = (float*)d_ws;   // NBLK floats

    k_fused<<<NBLK, 256, 0, stream>>>((const float4*)logits, logits, label, partials);
    k_final<<<1, 256, 0, stream>>>(partials, (float*)d_out);
}